// Round 10
// baseline (282.783 us; speedup 1.0000x reference)
//
#include <hip/hip_runtime.h>

typedef __bf16 bf16_t;
typedef bf16_t bf16x8 __attribute__((ext_vector_type(8)));
typedef float f32x4 __attribute__((ext_vector_type(4)));

#define N_PTS 8192
#define C_DIM 256
#define K_NN 16
#define Q_BLK 4              // measured optimum (r7: 90us; Q=8: 99us, Q=16: 167us)
#define KNN_BLOCKS (N_PTS / Q_BLK)   // 2048
#define PROJ_BLOCKS (128 * 3)        // 128 row-blocks x 3 matrices

// ---------------------------------------------------------------- prep: weights -> MFMA B-fragment-major bf16
// Wt[((t*8+kb)*512) + lm*32 + q*8 + e] = W[k = kb*32+q*8+e][n = t*16+lm].
__global__ __launch_bounds__(256) void prep_weights_kernel(
    const float* __restrict__ w0, const float* __restrict__ w1,
    const float* __restrict__ w2, const float* __restrict__ w3,
    const float* __restrict__ w4, bf16_t* __restrict__ wt_base) {
    int m = blockIdx.y;
    const float* src = (m == 0) ? w0 : (m == 1) ? w1 : (m == 2) ? w2 : (m == 3) ? w3 : w4;
    bf16_t* dst = wt_base + m * (C_DIM * C_DIM);
#pragma unroll
    for (int i = 0; i < 4; ++i) {
        int o = blockIdx.x * 1024 + i * 256 + threadIdx.x;
        int tkb = o >> 9;
        int rem = o & 511;
        int lm = rem >> 5;
        int r = rem & 31;
        int k = (tkb & 7) * 32 + r;
        int n = (tkb >> 3) * 16 + lm;
        dst[o] = (bf16_t)src[k * C_DIM + n];
    }
}

// ---------------------------------------------------------------- stage1: knn (blocks 0..2047) | proj (blocks 2048..2431)
// knn: 4 queries/block, d2 bits emulate numpy ref exactly (validated r3-r9):
//   sq = (fl(x^2)+fl(y^2))+fl(z^2); dot = fma(z,z',fma(y,y',fl(x*x')));
//   d2 = fl(fl(sq_i+sq_j) - fl(2*dot)); ties -> lower index.
// proj: T/P/G = feats@{theta,phi,g}+b; A loaded f32 and cvt'd in-reg (fb eliminated);
//   B fragments preloaded per wave (reg-resident), 4 row-tiles looped.
// Independence: knn touches coords/idx; proj touches feats/wt/T/Pb/Gb — no overlap.
// Co-scheduling rationale: knn is VALU/latency-bound, proj MFMA/memory-bound (m114:
// different-pipe waves on one CU overlap at ~max, not sum).
__global__ __launch_bounds__(256) void stage1_kernel(
    const float* __restrict__ coords, int* __restrict__ idx_out,
    const float* __restrict__ feats, const bf16_t* __restrict__ wt_base,
    const float* __restrict__ tb, const float* __restrict__ pbias, const float* __restrict__ gbias,
    float* __restrict__ T, bf16_t* __restrict__ Pb, bf16_t* __restrict__ Gb) {
    const int tid = threadIdx.x;
    const int wave = tid >> 6, lane = tid & 63;

    if (blockIdx.x < KNN_BLOCKS) {
        // ================================ KNN (Q=4, r7-validated 90us config)
        __shared__ float red16[Q_BLK][16];
        __shared__ unsigned long long cand[Q_BLK][256];
        __shared__ int cnt[Q_BLK];
        const int n0 = blockIdx.x * Q_BLK;

        if (tid < Q_BLK) cnt[tid] = 0;

        float qx[Q_BLK], qy[Q_BLK], qz[Q_BLK], sqi[Q_BLK];
#pragma unroll
        for (int q = 0; q < Q_BLK; ++q) {
            qx[q] = coords[3 * (n0 + q) + 0];
            qy[q] = coords[3 * (n0 + q) + 1];
            qz[q] = coords[3 * (n0 + q) + 2];
            sqi[q] = __fadd_rn(__fadd_rn(__fmul_rn(qx[q], qx[q]), __fmul_rn(qy[q], qy[q])),
                               __fmul_rn(qz[q], qz[q]));
        }

        const float INF = __int_as_float(0x7f800000);
        const float* cp = coords + tid * 96;

        // pass 1: per-thread min per query
        float lmin[Q_BLK] = {INF, INF, INF, INF};
#pragma unroll
        for (int c = 0; c < 4; ++c) {
            float buf[24];
#pragma unroll
            for (int v = 0; v < 6; ++v)
                *(float4*)(buf + v * 4) = *(const float4*)(cp + c * 24 + v * 4);
#pragma unroll
            for (int p = 0; p < 8; ++p) {
                float x = buf[3 * p + 0], y = buf[3 * p + 1], z = buf[3 * p + 2];
                float sqj = __fadd_rn(__fadd_rn(__fmul_rn(x, x), __fmul_rn(y, y)),
                                      __fmul_rn(z, z));
#pragma unroll
                for (int q = 0; q < Q_BLK; ++q) {
                    float dot = __fmaf_rn(z, qz[q], __fmaf_rn(y, qy[q], __fmul_rn(x, qx[q])));
                    float d2 = __fsub_rn(__fadd_rn(sqi[q], sqj), __fmul_rn(2.0f, dot));
                    lmin[q] = fminf(lmin[q], d2);
                }
            }
        }

        // 16 disjoint group-mins -> tau per query (tau >= 16th-NN dist, provable)
#pragma unroll
        for (int q = 0; q < Q_BLK; ++q) {
            float g = lmin[q];
            g = fminf(g, __shfl_xor(g, 1));
            g = fminf(g, __shfl_xor(g, 2));
            g = fminf(g, __shfl_xor(g, 4));
            g = fminf(g, __shfl_xor(g, 8));
            if ((lane & 15) == 0) red16[q][wave * 4 + (lane >> 4)] = g;
        }
        __syncthreads();

        float tau[Q_BLK];
#pragma unroll
        for (int q = 0; q < Q_BLK; ++q) {
            float t = red16[q][0];
#pragma unroll
            for (int i = 1; i < 16; ++i) t = fmaxf(t, red16[q][i]);
            tau[q] = t;
        }

        // pass 2: reload (L1-hot), identical d2 bits, compact survivors
#pragma unroll
        for (int c = 0; c < 4; ++c) {
            float buf[24];
#pragma unroll
            for (int v = 0; v < 6; ++v)
                *(float4*)(buf + v * 4) = *(const float4*)(cp + c * 24 + v * 4);
#pragma unroll
            for (int p = 0; p < 8; ++p) {
                float x = buf[3 * p + 0], y = buf[3 * p + 1], z = buf[3 * p + 2];
                float sqj = __fadd_rn(__fadd_rn(__fmul_rn(x, x), __fmul_rn(y, y)),
                                      __fmul_rn(z, z));
                int j = tid * 32 + c * 8 + p;
#pragma unroll
                for (int q = 0; q < Q_BLK; ++q) {
                    float dot = __fmaf_rn(z, qz[q], __fmaf_rn(y, qy[q], __fmul_rn(x, qx[q])));
                    float d2 = __fsub_rn(__fadd_rn(sqi[q], sqj), __fmul_rn(2.0f, dot));
                    if (d2 <= tau[q]) {
                        unsigned u = __float_as_uint(d2);
                        u = (u & 0x80000000u) ? ~u : (u | 0x80000000u);
                        int slot = atomicAdd(&cnt[q], 1);
                        if (slot < 256)
                            cand[q][slot] = (((unsigned long long)u) << 32) | (unsigned)j;
                    }
                }
            }
        }
        __syncthreads();

        // selection: wave w -> query w
        int m = cnt[wave]; if (m > 256) m = 256;
        unsigned long long k0 = ~0ull, k1 = ~0ull, k2 = ~0ull, k3 = ~0ull;
        if (lane < m) k0 = cand[wave][lane];
        if (lane + 64 < m) k1 = cand[wave][lane + 64];
        if (lane + 128 < m) k2 = cand[wave][lane + 128];
        if (lane + 192 < m) k3 = cand[wave][lane + 192];
        unsigned long long lm2 = k0; int li = 0;
        if (k1 < lm2) { lm2 = k1; li = 1; }
        if (k2 < lm2) { lm2 = k2; li = 2; }
        if (k3 < lm2) { lm2 = k3; li = 3; }
        int keep = 0;
#pragma unroll 1
        for (int r = 0; r < 16; ++r) {
            unsigned long long w = lm2;
#pragma unroll
            for (int off = 1; off < 64; off <<= 1) {
                unsigned long long o = __shfl_xor(w, off);
                w = (o < w) ? o : w;
            }
            if (lane == r) keep = (int)(unsigned)(w & 0xffffffffull);
            if (lm2 == w) {
                if (li == 0) k0 = ~0ull;
                else if (li == 1) k1 = ~0ull;
                else if (li == 2) k2 = ~0ull;
                else k3 = ~0ull;
                lm2 = k0; li = 0;
                if (k1 < lm2) { lm2 = k1; li = 1; }
                if (k2 < lm2) { lm2 = k2; li = 2; }
                if (k3 < lm2) { lm2 = k3; li = 3; }
            }
        }
        if (lane < 16) idx_out[(n0 + wave) * K_NN + lane] = keep;

    } else {
        // ================================ PROJ (f32 A, in-reg cvt; B reg-preload)
        const int pblk = blockIdx.x - KNN_BLOCKS;
        const int bx = pblk & 127;
        const int sel = pblk >> 7;
        const bf16_t* Wt = wt_base + sel * (C_DIM * C_DIM);
        const float* bias = (sel == 0) ? tb : (sel == 1) ? pbias : gbias;
        const int q = lane >> 4, lm = lane & 15;
        const int m0 = bx * 64;

        bf16x8 bfr[4][8];
#pragma unroll
        for (int ti = 0; ti < 4; ++ti)
#pragma unroll
            for (int kb = 0; kb < 8; ++kb)
                bfr[ti][kb] = *(const bf16x8*)(Wt + (((wave * 4 + ti) * 8 + kb) << 9) + lm * 32 + q * 8);

        float bv[4];
#pragma unroll
        for (int ti = 0; ti < 4; ++ti) bv[ti] = bias[(wave * 4 + ti) * 16 + lm];

#pragma unroll
        for (int p = 0; p < 4; ++p) {
            const float* arow = feats + (m0 + p * 16 + lm) * C_DIM + q * 8;
            bf16x8 a[8];
#pragma unroll
            for (int kb = 0; kb < 8; ++kb) {
                float4 u0 = *(const float4*)(arow + kb * 32);
                float4 u1 = *(const float4*)(arow + kb * 32 + 4);
                bf16x8 av;
                av[0] = (bf16_t)u0.x; av[1] = (bf16_t)u0.y; av[2] = (bf16_t)u0.z; av[3] = (bf16_t)u0.w;
                av[4] = (bf16_t)u1.x; av[5] = (bf16_t)u1.y; av[6] = (bf16_t)u1.z; av[7] = (bf16_t)u1.w;
                a[kb] = av;
            }
            f32x4 acc[4];
#pragma unroll
            for (int ti = 0; ti < 4; ++ti) acc[ti] = (f32x4){0.f, 0.f, 0.f, 0.f};
#pragma unroll
            for (int ti = 0; ti < 4; ++ti)
#pragma unroll
                for (int kb = 0; kb < 8; ++kb)
                    acc[ti] = __builtin_amdgcn_mfma_f32_16x16x32_bf16(a[kb], bfr[ti][kb], acc[ti], 0, 0, 0);

#pragma unroll
            for (int ti = 0; ti < 4; ++ti) {
                int c = (wave * 4 + ti) * 16 + lm;
#pragma unroll
                for (int r = 0; r < 4; ++r) {
                    float v = acc[ti][r] + bv[ti];
                    int off = (m0 + p * 16 + q * 4 + r) * C_DIM + c;
                    if (sel == 0) T[off] = v;
                    else if (sel == 1) Pb[off] = (bf16_t)v;
                    else Gb[off] = (bf16_t)v;
                }
            }
        }
    }
}

// ---------------------------------------------------------------- pe1 + pe2 GEMM + softmax + weighted G-sum (fused)
#define HPAD 264
#define P_BLK 8
#define HROWS (P_BLK * 16)
__global__ __launch_bounds__(256, 2) void pe2_fused_kernel(
    const float* __restrict__ coords, const int* __restrict__ idx,
    const float* __restrict__ T, const bf16_t* __restrict__ Pb, const bf16_t* __restrict__ Gb,
    const float* __restrict__ w1, const float* __restrict__ b1, const float* __restrict__ b2,
    const bf16_t* __restrict__ Wt2, bf16_t* __restrict__ yb) {
    __shared__ __align__(16) bf16_t h_lds[HROWS * HPAD];
    __shared__ float dxyz[HROWS][3];
    __shared__ int idxl[HROWS];
    const int tid = threadIdx.x;
    const int p0 = blockIdx.x * P_BLK;
    const int wave = tid >> 6, lane = tid & 63;
    const int q = lane >> 4, lm = lane & 15;

    bf16x8 bfr[4][8];
#pragma unroll
    for (int ti = 0; ti < 4; ++ti)
#pragma unroll
        for (int kb = 0; kb < 8; ++kb)
            bfr[ti][kb] = *(const bf16x8*)(Wt2 + (((wave * 4 + ti) * 8 + kb) << 9) + lm * 32 + q * 8);
    float b2c[4];
#pragma unroll
    for (int ti = 0; ti < 4; ++ti) b2c[ti] = b2[(wave * 4 + ti) * 16 + lm];

    if (tid < HROWS) {
        int n = p0 + (tid >> 4);
        int j = idx[n * K_NN + (tid & 15)];
        idxl[tid] = j;
        dxyz[tid][0] = coords[3 * j + 0] - coords[3 * n + 0];
        dxyz[tid][1] = coords[3 * j + 1] - coords[3 * n + 1];
        dxyz[tid][2] = coords[3 * j + 2] - coords[3 * n + 2];
    }
    __syncthreads();

    {   // pe1: h = relu(delta @ w1 + b1) -> LDS bf16
        int c = tid;
        float wx = w1[c], wy = w1[C_DIM + c], wz = w1[2 * C_DIM + c], bb = b1[c];
#pragma unroll 4
        for (int r = 0; r < HROWS; ++r) {
            float pre = dxyz[r][0] * wx + dxyz[r][1] * wy + dxyz[r][2] * wz + bb;
            h_lds[r * HPAD + c] = (bf16_t)fmaxf(pre, 0.0f);
        }
    }
    __syncthreads();

#pragma unroll 1
    for (int lp = 0; lp < P_BLK; ++lp) {
        const int n = p0 + lp;
        const bf16_t* hrow = h_lds + (lp * 16 + lm) * HPAD + q * 8;
        bf16x8 a[8];
#pragma unroll
        for (int kb = 0; kb < 8; ++kb) a[kb] = *(const bf16x8*)(hrow + kb * 32);
        f32x4 acc[4];
#pragma unroll
        for (int ti = 0; ti < 4; ++ti) acc[ti] = (f32x4){0.f, 0.f, 0.f, 0.f};
#pragma unroll
        for (int ti = 0; ti < 4; ++ti)
#pragma unroll
            for (int kb = 0; kb < 8; ++kb)
                acc[ti] = __builtin_amdgcn_mfma_f32_16x16x32_bf16(a[kb], bfr[ti][kb], acc[ti], 0, 0, 0);

        int jr[4];
#pragma unroll
        for (int r = 0; r < 4; ++r) jr[r] = idxl[lp * 16 + q * 4 + r];

#pragma unroll
        for (int ti = 0; ti < 4; ++ti) {
            int c = (wave * 4 + ti) * 16 + lm;
            float phi[4], gv[4];
#pragma unroll
            for (int r = 0; r < 4; ++r) {
                phi[r] = (float)Pb[jr[r] * C_DIM + c];
                gv[r]  = (float)Gb[jr[r] * C_DIM + c];
            }
            float Tn = T[n * C_DIM + c];
            float df[4];
#pragma unroll
            for (int r = 0; r < 4; ++r) {
                float pe = acc[ti][r] + b2c[ti];
                df[r] = (pe * (Tn - phi[r]) + pe) * 0.0625f;
            }
            float mx = fmaxf(fmaxf(df[0], df[1]), fmaxf(df[2], df[3]));
            mx = fmaxf(mx, __shfl_xor(mx, 16));
            mx = fmaxf(mx, __shfl_xor(mx, 32));
            float e[4], s = 0.f;
#pragma unroll
            for (int r = 0; r < 4; ++r) { e[r] = __expf(df[r] - mx); s += e[r]; }
            s += __shfl_xor(s, 16);
            s += __shfl_xor(s, 32);
            float inv = 1.0f / s;
            float y = 0.f;
#pragma unroll
            for (int r = 0; r < 4; ++r) y += e[r] * inv * gv[r];
            y += __shfl_xor(y, 16);
            y += __shfl_xor(y, 32);
            if (q == 0) yb[n * C_DIM + c] = (bf16_t)y;
        }
    }
}

// ---------------------------------------------------------------- final: out = y@W_w + W_b + feats
__global__ __launch_bounds__(256, 2) void final_kernel(
    const bf16_t* __restrict__ yb, const bf16_t* __restrict__ Wt,
    const float* __restrict__ Wb, const float* __restrict__ feats,
    float* __restrict__ out) {
    const int wave = threadIdx.x >> 6, lane = threadIdx.x & 63;
    const int q = lane >> 4, lm = lane & 15;
    const int m0 = blockIdx.x * 64;

    bf16x8 bfr[4][8];
#pragma unroll
    for (int ti = 0; ti < 4; ++ti)
#pragma unroll
        for (int kb = 0; kb < 8; ++kb)
            bfr[ti][kb] = *(const bf16x8*)(Wt + (((wave * 4 + ti) * 8 + kb) << 9) + lm * 32 + q * 8);
    float bv[4];
#pragma unroll
    for (int ti = 0; ti < 4; ++ti) bv[ti] = Wb[(wave * 4 + ti) * 16 + lm];

#pragma unroll
    for (int p = 0; p < 4; ++p) {
        const bf16_t* arow = yb + (m0 + p * 16 + lm) * C_DIM + q * 8;
        bf16x8 a[8];
#pragma unroll
        for (int kb = 0; kb < 8; ++kb) a[kb] = *(const bf16x8*)(arow + kb * 32);
        f32x4 acc[4];
#pragma unroll
        for (int ti = 0; ti < 4; ++ti) acc[ti] = (f32x4){0.f, 0.f, 0.f, 0.f};
#pragma unroll
        for (int ti = 0; ti < 4; ++ti)
#pragma unroll
            for (int kb = 0; kb < 8; ++kb)
                acc[ti] = __builtin_amdgcn_mfma_f32_16x16x32_bf16(a[kb], bfr[ti][kb], acc[ti], 0, 0, 0);

#pragma unroll
        for (int ti = 0; ti < 4; ++ti) {
            int c = (wave * 4 + ti) * 16 + lm;
#pragma unroll
            for (int r = 0; r < 4; ++r) {
                int off = (m0 + p * 16 + q * 4 + r) * C_DIM + c;
                out[off] = acc[ti][r] + bv[ti] + feats[off];
            }
        }
    }
}

// ---------------------------------------------------------------- launch
extern "C" void kernel_launch(void* const* d_in, const int* in_sizes, int n_in,
                              void* d_out, int out_size, void* d_ws, size_t ws_size,
                              hipStream_t stream) {
    const float* coords = (const float*)d_in[0];
    const float* feats  = (const float*)d_in[1];
    const float* theta_w = (const float*)d_in[2];
    const float* theta_b = (const float*)d_in[3];
    const float* phi_w   = (const float*)d_in[4];
    const float* phi_b   = (const float*)d_in[5];
    const float* g_w     = (const float*)d_in[6];
    const float* g_b     = (const float*)d_in[7];
    const float* pe1_w1  = (const float*)d_in[8];
    const float* pe1_b1  = (const float*)d_in[9];
    const float* pe1_w2  = (const float*)d_in[10];
    const float* pe1_b2  = (const float*)d_in[11];
    const float* W_w     = (const float*)d_in[12];
    const float* W_b     = (const float*)d_in[13];
    float* out = (float*)d_out;

    char* w = (char*)d_ws;
    size_t off = 0;
    int* idx = (int*)(w + off);        off += (size_t)N_PTS * K_NN * 4;       // 512 KB
    bf16_t* wt = (bf16_t*)(w + off);   off += (size_t)5 * C_DIM * C_DIM * 2;  // 640 KB
    float* T = (float*)(w + off);      off += (size_t)N_PTS * C_DIM * 4;      // 8 MB
    bf16_t* Pb = (bf16_t*)(w + off);   off += (size_t)N_PTS * C_DIM * 2;      // 4 MB
    bf16_t* Gb = (bf16_t*)(w + off);   off += (size_t)N_PTS * C_DIM * 2;      // 4 MB
    bf16_t* yb = (bf16_t*)(w + off);   off += (size_t)N_PTS * C_DIM * 2;      // 4 MB
    (void)ws_size; (void)in_sizes; (void)n_in; (void)out_size;

    prep_weights_kernel<<<dim3(64, 5), 256, 0, stream>>>(theta_w, phi_w, g_w, pe1_w2, W_w, wt);
    stage1_kernel<<<KNN_BLOCKS + PROJ_BLOCKS, 256, 0, stream>>>(
        coords, idx, feats, wt, theta_b, phi_b, g_b, T, Pb, Gb);
    pe2_fused_kernel<<<N_PTS / P_BLK, 256, 0, stream>>>(coords, idx, T, Pb, Gb,
                                                        pe1_w1, pe1_b1, pe1_b2,
                                                        wt + 3 * C_DIM * C_DIM, yb);
    final_kernel<<<N_PTS / 64, 256, 0, stream>>>(yb, wt + 4 * C_DIM * C_DIM, W_b, feats, out);
}

// Round 11
// 272.536 us; speedup vs baseline: 1.0376x; 1.0376x over previous
//
#include <hip/hip_runtime.h>

typedef __bf16 bf16_t;
typedef bf16_t bf16x8 __attribute__((ext_vector_type(8)));
typedef float f32x4 __attribute__((ext_vector_type(4)));

#define N_PTS 8192
#define C_DIM 256
#define K_NN 16
#define Q_BLK 4              // measured optimum (r7: 90us; Q=8: 99us, Q=16: 167us)
#define KNN_BLOCKS (N_PTS / Q_BLK)   // 2048
#define PROJ_BLOCKS (128 * 3)        // 128 row-blocks x 3 matrices
// grid = 128 groups x (16 knn + 3 proj) = 2432, interleaved so proj co-resides with knn

// ---------------------------------------------------------------- prep: weights -> MFMA B-fragment-major bf16
// Wt[((t*8+kb)*512) + lm*32 + q*8 + e] = W[k = kb*32+q*8+e][n = t*16+lm].
__global__ __launch_bounds__(256) void prep_weights_kernel(
    const float* __restrict__ w0, const float* __restrict__ w1,
    const float* __restrict__ w2, const float* __restrict__ w3,
    const float* __restrict__ w4, bf16_t* __restrict__ wt_base) {
    int m = blockIdx.y;
    const float* src = (m == 0) ? w0 : (m == 1) ? w1 : (m == 2) ? w2 : (m == 3) ? w3 : w4;
    bf16_t* dst = wt_base + m * (C_DIM * C_DIM);
#pragma unroll
    for (int i = 0; i < 4; ++i) {
        int o = blockIdx.x * 1024 + i * 256 + threadIdx.x;
        int tkb = o >> 9;
        int rem = o & 511;
        int lm = rem >> 5;
        int r = rem & 31;
        int k = (tkb & 7) * 32 + r;
        int n = (tkb >> 3) * 16 + lm;
        dst[o] = (bf16_t)src[k * C_DIM + n];
    }
}

// ---------------------------------------------------------------- stage1: interleaved knn | proj
// knn: 4 queries/block, d2 bits emulate numpy ref exactly (validated r3-r10):
//   sq = (fl(x^2)+fl(y^2))+fl(z^2); dot = fma(z,z',fma(y,y',fl(x*x')));
//   d2 = fl(fl(sq_i+sq_j) - fl(2*dot)); ties -> lower index.
// Selection: rank-by-counting over <=256 unique (ordered_d2,idx) u64 keys in LDS —
//   no serial argmin rounds, no shfl chains (r10 post-mortem: 16-round argmin was
//   a ~6K-cycle latency sink per wave).
// proj: T/P/G = feats@{theta,phi,g}+b; f32 A cvt'd in-reg; B reg-preloaded.
__global__ __launch_bounds__(256) void stage1_kernel(
    const float* __restrict__ coords, int* __restrict__ idx_out,
    const float* __restrict__ feats, const bf16_t* __restrict__ wt_base,
    const float* __restrict__ tb, const float* __restrict__ pbias, const float* __restrict__ gbias,
    float* __restrict__ T, bf16_t* __restrict__ Pb, bf16_t* __restrict__ Gb) {
    const int tid = threadIdx.x;
    const int wave = tid >> 6, lane = tid & 63;
    const int grp = blockIdx.x / 19, rem19 = blockIdx.x % 19;

    if (rem19 < 16) {
        // ================================ KNN (Q=4)
        __shared__ float red16[Q_BLK][16];
        __shared__ unsigned long long cand[Q_BLK][256];
        __shared__ int cnt[Q_BLK];
        const int n0 = (grp * 16 + rem19) * Q_BLK;

        if (tid < Q_BLK) cnt[tid] = 0;

        float qx[Q_BLK], qy[Q_BLK], qz[Q_BLK], sqi[Q_BLK];
#pragma unroll
        for (int q = 0; q < Q_BLK; ++q) {
            qx[q] = coords[3 * (n0 + q) + 0];
            qy[q] = coords[3 * (n0 + q) + 1];
            qz[q] = coords[3 * (n0 + q) + 2];
            sqi[q] = __fadd_rn(__fadd_rn(__fmul_rn(qx[q], qx[q]), __fmul_rn(qy[q], qy[q])),
                               __fmul_rn(qz[q], qz[q]));
        }

        const float INF = __int_as_float(0x7f800000);
        const float* cp = coords + tid * 96;

        // pass 1: per-thread min per query
        float lmin[Q_BLK] = {INF, INF, INF, INF};
#pragma unroll
        for (int c = 0; c < 4; ++c) {
            float buf[24];
#pragma unroll
            for (int v = 0; v < 6; ++v)
                *(float4*)(buf + v * 4) = *(const float4*)(cp + c * 24 + v * 4);
#pragma unroll
            for (int p = 0; p < 8; ++p) {
                float x = buf[3 * p + 0], y = buf[3 * p + 1], z = buf[3 * p + 2];
                float sqj = __fadd_rn(__fadd_rn(__fmul_rn(x, x), __fmul_rn(y, y)),
                                      __fmul_rn(z, z));
#pragma unroll
                for (int q = 0; q < Q_BLK; ++q) {
                    float dot = __fmaf_rn(z, qz[q], __fmaf_rn(y, qy[q], __fmul_rn(x, qx[q])));
                    float d2 = __fsub_rn(__fadd_rn(sqi[q], sqj), __fmul_rn(2.0f, dot));
                    lmin[q] = fminf(lmin[q], d2);
                }
            }
        }

        // 16 disjoint group-mins -> tau per query (tau >= 16th-NN dist, provable)
#pragma unroll
        for (int q = 0; q < Q_BLK; ++q) {
            float g = lmin[q];
            g = fminf(g, __shfl_xor(g, 1));
            g = fminf(g, __shfl_xor(g, 2));
            g = fminf(g, __shfl_xor(g, 4));
            g = fminf(g, __shfl_xor(g, 8));
            if ((lane & 15) == 0) red16[q][wave * 4 + (lane >> 4)] = g;
        }
        __syncthreads();

        float tau[Q_BLK];
#pragma unroll
        for (int q = 0; q < Q_BLK; ++q) {
            float t = red16[q][0];
#pragma unroll
            for (int i = 1; i < 16; ++i) t = fmaxf(t, red16[q][i]);
            tau[q] = t;
        }

        // pass 2: reload (L1-hot), identical d2 bits, compact survivors
#pragma unroll
        for (int c = 0; c < 4; ++c) {
            float buf[24];
#pragma unroll
            for (int v = 0; v < 6; ++v)
                *(float4*)(buf + v * 4) = *(const float4*)(cp + c * 24 + v * 4);
#pragma unroll
            for (int p = 0; p < 8; ++p) {
                float x = buf[3 * p + 0], y = buf[3 * p + 1], z = buf[3 * p + 2];
                float sqj = __fadd_rn(__fadd_rn(__fmul_rn(x, x), __fmul_rn(y, y)),
                                      __fmul_rn(z, z));
                int j = tid * 32 + c * 8 + p;
#pragma unroll
                for (int q = 0; q < Q_BLK; ++q) {
                    float dot = __fmaf_rn(z, qz[q], __fmaf_rn(y, qy[q], __fmul_rn(x, qx[q])));
                    float d2 = __fsub_rn(__fadd_rn(sqi[q], sqj), __fmul_rn(2.0f, dot));
                    if (d2 <= tau[q]) {
                        unsigned u = __float_as_uint(d2);
                        u = (u & 0x80000000u) ? ~u : (u | 0x80000000u);
                        int slot = atomicAdd(&cnt[q], 1);
                        if (slot < 256)
                            cand[q][slot] = (((unsigned long long)u) << 32) | (unsigned)j;
                    }
                }
            }
        }
        __syncthreads();

        // selection: wave w -> query w; rank-by-counting (keys unique, m>=16 by tau proof)
        {
            int m = cnt[wave]; if (m > 256) m = 256;
#pragma unroll 1
            for (int base = 0; base < 256; base += 64) {
                int l = base + lane;
                if (l < m) {
                    unsigned long long k = cand[wave][l];
                    int rank = 0;
#pragma unroll 4
                    for (int j = 0; j < m; ++j) rank += (cand[wave][j] < k) ? 1 : 0;
                    if (rank < K_NN)
                        idx_out[(n0 + wave) * K_NN + rank] =
                            (int)(unsigned)(k & 0xffffffffull);
                }
            }
        }

    } else {
        // ================================ PROJ (f32 A, in-reg cvt; B reg-preload)
        const int pblk = grp * 3 + (rem19 - 16);
        const int bx = pblk & 127;
        const int sel = pblk >> 7;
        const bf16_t* Wt = wt_base + sel * (C_DIM * C_DIM);
        const float* bias = (sel == 0) ? tb : (sel == 1) ? pbias : gbias;
        const int q = lane >> 4, lm = lane & 15;
        const int m0 = bx * 64;

        bf16x8 bfr[4][8];
#pragma unroll
        for (int ti = 0; ti < 4; ++ti)
#pragma unroll
            for (int kb = 0; kb < 8; ++kb)
                bfr[ti][kb] = *(const bf16x8*)(Wt + (((wave * 4 + ti) * 8 + kb) << 9) + lm * 32 + q * 8);

        float bv[4];
#pragma unroll
        for (int ti = 0; ti < 4; ++ti) bv[ti] = bias[(wave * 4 + ti) * 16 + lm];

#pragma unroll
        for (int p = 0; p < 4; ++p) {
            const float* arow = feats + (m0 + p * 16 + lm) * C_DIM + q * 8;
            bf16x8 a[8];
#pragma unroll
            for (int kb = 0; kb < 8; ++kb) {
                float4 u0 = *(const float4*)(arow + kb * 32);
                float4 u1 = *(const float4*)(arow + kb * 32 + 4);
                bf16x8 av;
                av[0] = (bf16_t)u0.x; av[1] = (bf16_t)u0.y; av[2] = (bf16_t)u0.z; av[3] = (bf16_t)u0.w;
                av[4] = (bf16_t)u1.x; av[5] = (bf16_t)u1.y; av[6] = (bf16_t)u1.z; av[7] = (bf16_t)u1.w;
                a[kb] = av;
            }
            f32x4 acc[4];
#pragma unroll
            for (int ti = 0; ti < 4; ++ti) acc[ti] = (f32x4){0.f, 0.f, 0.f, 0.f};
#pragma unroll
            for (int ti = 0; ti < 4; ++ti)
#pragma unroll
                for (int kb = 0; kb < 8; ++kb)
                    acc[ti] = __builtin_amdgcn_mfma_f32_16x16x32_bf16(a[kb], bfr[ti][kb], acc[ti], 0, 0, 0);

#pragma unroll
            for (int ti = 0; ti < 4; ++ti) {
                int c = (wave * 4 + ti) * 16 + lm;
#pragma unroll
                for (int r = 0; r < 4; ++r) {
                    float v = acc[ti][r] + bv[ti];
                    int off = (m0 + p * 16 + q * 4 + r) * C_DIM + c;
                    if (sel == 0) T[off] = v;
                    else if (sel == 1) Pb[off] = (bf16_t)v;
                    else Gb[off] = (bf16_t)v;
                }
            }
        }
    }
}

// ---------------------------------------------------------------- pe1 + pe2 GEMM + softmax + weighted G-sum (fused)
#define HPAD 264
#define P_BLK 8
#define HROWS (P_BLK * 16)
__global__ __launch_bounds__(256, 2) void pe2_fused_kernel(
    const float* __restrict__ coords, const int* __restrict__ idx,
    const float* __restrict__ T, const bf16_t* __restrict__ Pb, const bf16_t* __restrict__ Gb,
    const float* __restrict__ w1, const float* __restrict__ b1, const float* __restrict__ b2,
    const bf16_t* __restrict__ Wt2, bf16_t* __restrict__ yb) {
    __shared__ __align__(16) bf16_t h_lds[HROWS * HPAD];
    __shared__ float dxyz[HROWS][3];
    __shared__ int idxl[HROWS];
    const int tid = threadIdx.x;
    const int p0 = blockIdx.x * P_BLK;
    const int wave = tid >> 6, lane = tid & 63;
    const int q = lane >> 4, lm = lane & 15;

    bf16x8 bfr[4][8];
#pragma unroll
    for (int ti = 0; ti < 4; ++ti)
#pragma unroll
        for (int kb = 0; kb < 8; ++kb)
            bfr[ti][kb] = *(const bf16x8*)(Wt2 + (((wave * 4 + ti) * 8 + kb) << 9) + lm * 32 + q * 8);
    float b2c[4];
#pragma unroll
    for (int ti = 0; ti < 4; ++ti) b2c[ti] = b2[(wave * 4 + ti) * 16 + lm];

    if (tid < HROWS) {
        int n = p0 + (tid >> 4);
        int j = idx[n * K_NN + (tid & 15)];
        idxl[tid] = j;
        dxyz[tid][0] = coords[3 * j + 0] - coords[3 * n + 0];
        dxyz[tid][1] = coords[3 * j + 1] - coords[3 * n + 1];
        dxyz[tid][2] = coords[3 * j + 2] - coords[3 * n + 2];
    }
    __syncthreads();

    {   // pe1: h = relu(delta @ w1 + b1) -> LDS bf16
        int c = tid;
        float wx = w1[c], wy = w1[C_DIM + c], wz = w1[2 * C_DIM + c], bb = b1[c];
#pragma unroll 4
        for (int r = 0; r < HROWS; ++r) {
            float pre = dxyz[r][0] * wx + dxyz[r][1] * wy + dxyz[r][2] * wz + bb;
            h_lds[r * HPAD + c] = (bf16_t)fmaxf(pre, 0.0f);
        }
    }
    __syncthreads();

#pragma unroll 1
    for (int lp = 0; lp < P_BLK; ++lp) {
        const int n = p0 + lp;
        const bf16_t* hrow = h_lds + (lp * 16 + lm) * HPAD + q * 8;
        bf16x8 a[8];
#pragma unroll
        for (int kb = 0; kb < 8; ++kb) a[kb] = *(const bf16x8*)(hrow + kb * 32);
        f32x4 acc[4];
#pragma unroll
        for (int ti = 0; ti < 4; ++ti) acc[ti] = (f32x4){0.f, 0.f, 0.f, 0.f};
#pragma unroll
        for (int ti = 0; ti < 4; ++ti)
#pragma unroll
            for (int kb = 0; kb < 8; ++kb)
                acc[ti] = __builtin_amdgcn_mfma_f32_16x16x32_bf16(a[kb], bfr[ti][kb], acc[ti], 0, 0, 0);

        int jr[4];
#pragma unroll
        for (int r = 0; r < 4; ++r) jr[r] = idxl[lp * 16 + q * 4 + r];

#pragma unroll
        for (int ti = 0; ti < 4; ++ti) {
            int c = (wave * 4 + ti) * 16 + lm;
            float phi[4], gv[4];
#pragma unroll
            for (int r = 0; r < 4; ++r) {
                phi[r] = (float)Pb[jr[r] * C_DIM + c];
                gv[r]  = (float)Gb[jr[r] * C_DIM + c];
            }
            float Tn = T[n * C_DIM + c];
            float df[4];
#pragma unroll
            for (int r = 0; r < 4; ++r) {
                float pe = acc[ti][r] + b2c[ti];
                df[r] = (pe * (Tn - phi[r]) + pe) * 0.0625f;
            }
            float mx = fmaxf(fmaxf(df[0], df[1]), fmaxf(df[2], df[3]));
            mx = fmaxf(mx, __shfl_xor(mx, 16));
            mx = fmaxf(mx, __shfl_xor(mx, 32));
            float e[4], s = 0.f;
#pragma unroll
            for (int r = 0; r < 4; ++r) { e[r] = __expf(df[r] - mx); s += e[r]; }
            s += __shfl_xor(s, 16);
            s += __shfl_xor(s, 32);
            float inv = 1.0f / s;
            float y = 0.f;
#pragma unroll
            for (int r = 0; r < 4; ++r) y += e[r] * inv * gv[r];
            y += __shfl_xor(y, 16);
            y += __shfl_xor(y, 32);
            if (q == 0) yb[n * C_DIM + c] = (bf16_t)y;
        }
    }
}

// ---------------------------------------------------------------- final: out = y@W_w + W_b + feats
__global__ __launch_bounds__(256, 2) void final_kernel(
    const bf16_t* __restrict__ yb, const bf16_t* __restrict__ Wt,
    const float* __restrict__ Wb, const float* __restrict__ feats,
    float* __restrict__ out) {
    const int wave = threadIdx.x >> 6, lane = threadIdx.x & 63;
    const int q = lane >> 4, lm = lane & 15;
    const int m0 = blockIdx.x * 64;

    bf16x8 bfr[4][8];
#pragma unroll
    for (int ti = 0; ti < 4; ++ti)
#pragma unroll
        for (int kb = 0; kb < 8; ++kb)
            bfr[ti][kb] = *(const bf16x8*)(Wt + (((wave * 4 + ti) * 8 + kb) << 9) + lm * 32 + q * 8);
    float bv[4];
#pragma unroll
    for (int ti = 0; ti < 4; ++ti) bv[ti] = Wb[(wave * 4 + ti) * 16 + lm];

#pragma unroll
    for (int p = 0; p < 4; ++p) {
        const bf16_t* arow = yb + (m0 + p * 16 + lm) * C_DIM + q * 8;
        bf16x8 a[8];
#pragma unroll
        for (int kb = 0; kb < 8; ++kb) a[kb] = *(const bf16x8*)(arow + kb * 32);
        f32x4 acc[4];
#pragma unroll
        for (int ti = 0; ti < 4; ++ti) acc[ti] = (f32x4){0.f, 0.f, 0.f, 0.f};
#pragma unroll
        for (int ti = 0; ti < 4; ++ti)
#pragma unroll
            for (int kb = 0; kb < 8; ++kb)
                acc[ti] = __builtin_amdgcn_mfma_f32_16x16x32_bf16(a[kb], bfr[ti][kb], acc[ti], 0, 0, 0);

#pragma unroll
        for (int ti = 0; ti < 4; ++ti) {
            int c = (wave * 4 + ti) * 16 + lm;
#pragma unroll
            for (int r = 0; r < 4; ++r) {
                int off = (m0 + p * 16 + q * 4 + r) * C_DIM + c;
                out[off] = acc[ti][r] + bv[ti] + feats[off];
            }
        }
    }
}

// ---------------------------------------------------------------- launch
extern "C" void kernel_launch(void* const* d_in, const int* in_sizes, int n_in,
                              void* d_out, int out_size, void* d_ws, size_t ws_size,
                              hipStream_t stream) {
    const float* coords = (const float*)d_in[0];
    const float* feats  = (const float*)d_in[1];
    const float* theta_w = (const float*)d_in[2];
    const float* theta_b = (const float*)d_in[3];
    const float* phi_w   = (const float*)d_in[4];
    const float* phi_b   = (const float*)d_in[5];
    const float* g_w     = (const float*)d_in[6];
    const float* g_b     = (const float*)d_in[7];
    const float* pe1_w1  = (const float*)d_in[8];
    const float* pe1_b1  = (const float*)d_in[9];
    const float* pe1_w2  = (const float*)d_in[10];
    const float* pe1_b2  = (const float*)d_in[11];
    const float* W_w     = (const float*)d_in[12];
    const float* W_b     = (const float*)d_in[13];
    float* out = (float*)d_out;

    char* w = (char*)d_ws;
    size_t off = 0;
    int* idx = (int*)(w + off);        off += (size_t)N_PTS * K_NN * 4;       // 512 KB
    bf16_t* wt = (bf16_t*)(w + off);   off += (size_t)5 * C_DIM * C_DIM * 2;  // 640 KB
    float* T = (float*)(w + off);      off += (size_t)N_PTS * C_DIM * 4;      // 8 MB
    bf16_t* Pb = (bf16_t*)(w + off);   off += (size_t)N_PTS * C_DIM * 2;      // 4 MB
    bf16_t* Gb = (bf16_t*)(w + off);   off += (size_t)N_PTS * C_DIM * 2;      // 4 MB
    bf16_t* yb = (bf16_t*)(w + off);   off += (size_t)N_PTS * C_DIM * 2;      // 4 MB
    (void)ws_size; (void)in_sizes; (void)n_in; (void)out_size;

    prep_weights_kernel<<<dim3(64, 5), 256, 0, stream>>>(theta_w, phi_w, g_w, pe1_w2, W_w, wt);
    stage1_kernel<<<KNN_BLOCKS + PROJ_BLOCKS, 256, 0, stream>>>(
        coords, idx, feats, wt, theta_b, phi_b, g_b, T, Pb, Gb);
    pe2_fused_kernel<<<N_PTS / P_BLK, 256, 0, stream>>>(coords, idx, T, Pb, Gb,
                                                        pe1_w1, pe1_b1, pe1_b2,
                                                        wt + 3 * C_DIM * C_DIM, yb);
    final_kernel<<<N_PTS / 64, 256, 0, stream>>>(yb, wt + 4 * C_DIM * C_DIM, W_b, feats, out);
}